// Round 6
// baseline (552.416 us; speedup 1.0000x reference)
//
#include <hip/hip_runtime.h>
#include <hip/hip_bf16.h>
#include <hip/hip_fp16.h>

typedef _Float16 f16;
typedef __attribute__((ext_vector_type(8))) _Float16 f16x8;
typedef __attribute__((ext_vector_type(4))) _Float16 f16x4;
typedef __attribute__((ext_vector_type(4))) float f32x4;
typedef __attribute__((address_space(1))) const unsigned int gu32;
typedef __attribute__((address_space(3))) unsigned int lu32;

#define BQ 16
#define SQ 1024
#define HQ 512
#define MQ (BQ*SQ)          // 16384 rows total
#define PLANE ((size_t)MQ*512)

// ---- workspace layout (bytes). Aliasing:
//   ANORM aliases XF16 planes 0-1 (dead after gate GEMMs)
//   HN    aliases XF16 plane 2 (first written in layer 0, after gates)
//   YT    aliases T    (T dead after gate GEMMs)
#define OFF_WG1T 0ul
#define OFF_WG2T 524288ul
#define OFF_W0T  1048576ul
#define OFF_W1T  2621440ul
#define OFF_W2T  3145728ul
#define OFF_WENT 3670016ul
#define OFF_ENTS 3672064ul
#define OFF_DSI  3868672ul
#define OFF_XF16 3934208ul
#define OFF_ANORM OFF_XF16
#define OFF_HN   (OFF_XF16 + 33554432ul)
#define OFF_T    71043072ul
#define OFF_YT   OFF_T
#define OFF_HCAT 104597504ul
// total = 104597504 + 50331648 = 154929152 bytes (~148 MB)

// async global->LDS, 16B per lane; LDS dest is wave-uniform base + lane*16
__device__ __forceinline__ void gl16(f16* lds, const f16* g) {
    __builtin_amdgcn_global_load_lds(
        (gu32*)(const __attribute__((address_space(1))) f16*)g,
        (lu32*)(__attribute__((address_space(3))) f16*)lds, 16, 0, 0);
}

// ---------------- weight prep: fold gate algebra, transpose to [N][K], cast f16
__global__ __launch_bounds__(256) void k_prep(
    const float* __restrict__ gW, const float* __restrict__ W0,
    const float* __restrict__ W1, const float* __restrict__ W2,
    f16* __restrict__ Wg1t, f16* __restrict__ Wg2t, f16* __restrict__ W0t,
    f16* __restrict__ W1t, f16* __restrict__ W2t, float* __restrict__ went)
{
    int i = blockIdx.x * 256 + threadIdx.x;      // grid covers 1536*512
    if (i < 1536*512) {
        int n = i & 511, k = i >> 9;             // k < 1536
        W0t[(size_t)n*1536 + k] = (f16)W0[(size_t)k*512 + n];
    }
    if (i < 512*512) {
        int n = i >> 9, k = i & 511;
        float wa = gW[(size_t)k*512 + n];
        float wb = gW[(size_t)(512 + k)*512 + n];
        float wr = gW[(size_t)(1024 + k)*512 + n];
        Wg1t[(size_t)n*512 + k] = (f16)(wa + wb - 0.5f*wr);
        Wg2t[(size_t)n*512 + k] = (f16)(0.5f*wr);
        W1t[(size_t)n*512 + k]  = (f16)W1[(size_t)k*512 + n];
        W2t[(size_t)n*512 + k]  = (f16)W2[(size_t)k*512 + n];
    }
    if (i < 512) went[i] = gW[(size_t)1536*512 + i];
}

// ---------------- entropy per row per modality + f16 casts + sum plane
// single-pass identity: S=sum|x|, T=sum|x|*log|x|, S'=S+eps
//   entropy = -sum fn*log(fn) = log(S')*(S/S') - T/S'
__global__ __launch_bounds__(256) void k_ent(
    const float* __restrict__ t, const float* __restrict__ a, const float* __restrict__ v,
    f16* __restrict__ xf, float* __restrict__ ents)
{
    int wave = threadIdx.x >> 6, lane = threadIdx.x & 63;
    int row = blockIdx.x * 4 + wave;
    const float* ptrs[3] = {t, a, v};
    float4 x[3][2];
#pragma unroll
    for (int m = 0; m < 3; m++) {
        const float4* p = (const float4*)(ptrs[m] + (size_t)row*512);
        x[m][0] = p[lane*2];
        x[m][1] = p[lane*2 + 1];
    }
    float s[3], tt[3];
#pragma unroll
    for (int m = 0; m < 3; m++) {
        float xs[8] = {x[m][0].x,x[m][0].y,x[m][0].z,x[m][0].w,
                       x[m][1].x,x[m][1].y,x[m][1].z,x[m][1].w};
        s[m] = 0.f; tt[m] = 0.f;
#pragma unroll
        for (int j = 0; j < 8; j++) {
            float ab = fabsf(xs[j]);
            s[m]  += ab;
            tt[m] += ab * __logf(ab + 1e-12f);
        }
    }
    // 6 independent butterfly chains interleaved
#pragma unroll
    for (int off = 32; off; off >>= 1) {
#pragma unroll
        for (int m = 0; m < 3; m++) {
            s[m]  += __shfl_xor(s[m],  off);
            tt[m] += __shfl_xor(tt[m], off);
        }
    }
    if (lane == 0) {
#pragma unroll
        for (int m = 0; m < 3; m++) {
            float sp = s[m] + 1e-10f;
            ents[m*MQ + row] = __logf(sp) * (s[m]/sp) - tt[m]/sp;
        }
    }
    // f16 casts + sum plane
    float sum8[8];
#pragma unroll
    for (int j = 0; j < 8; j++) sum8[j] = 0.f;
#pragma unroll
    for (int m = 0; m < 3; m++) {
        float xs[8] = {x[m][0].x,x[m][0].y,x[m][0].z,x[m][0].w,
                       x[m][1].x,x[m][1].y,x[m][1].z,x[m][1].w};
        f16x8 o;
#pragma unroll
        for (int j = 0; j < 8; j++) { o[j] = (f16)xs[j]; sum8[j] += xs[j]; }
        *(f16x8*)(xf + ((size_t)m*MQ + row)*512 + lane*8) = o;
    }
    f16x8 o;
#pragma unroll
    for (int j = 0; j < 8; j++) o[j] = (f16)sum8[j];
    *(f16x8*)(xf + ((size_t)3*MQ + row)*512 + lane*8) = o;
}

// ---------------- dsi = (rowsum(0.5*(sp+tg)) + 1 + eps)^-1/2
__global__ __launch_bounds__(256) void k_dsi(
    const float* __restrict__ sp, const float* __restrict__ tg, float* __restrict__ dsi)
{
    int wave = threadIdx.x >> 6, lane = threadIdx.x & 63;
    int row = blockIdx.x * 4 + wave;     // 0..16383 (b*1024+i)
    const float4* p1 = (const float4*)(sp + (size_t)row*1024);
    const float4* p2 = (const float4*)(tg + (size_t)row*1024);
    float s = 0.f;
#pragma unroll
    for (int c = 0; c < 4; c++) {
        float4 x = p1[c*64 + lane], y = p2[c*64 + lane];
        s += x.x + x.y + x.z + x.w + y.x + y.y + y.z + y.w;
    }
#pragma unroll
    for (int off = 32; off; off >>= 1) s += __shfl_xor(s, off);
    if (lane == 0) dsi[row] = 1.f / sqrtf(0.5f*s + 1.f + 1e-10f);
}

// ---------------- norm_adj build (f16)
__global__ __launch_bounds__(256) void k_anorm(
    const float* __restrict__ sp, const float* __restrict__ tg,
    const float* __restrict__ dsi, f16* __restrict__ an)
{
    size_t t = (size_t)blockIdx.x*256 + threadIdx.x;   // 4 elems per thread
    int j4 = (int)(t & 255) * 4;
    int i  = (int)(t >> 8) & 1023;
    int b  = (int)(t >> 18);
    size_t base = ((size_t)b << 20) + (size_t)i*1024 + j4;
    float4 x = *(const float4*)(sp + base);
    float4 y = *(const float4*)(tg + base);
    float4 dj = *(const float4*)(dsi + b*1024 + j4);
    float di = dsi[b*1024 + i];
    float v0 = 0.5f*(x.x + y.x) + (i == j4+0 ? 1.f : 0.f);
    float v1 = 0.5f*(x.y + y.y) + (i == j4+1 ? 1.f : 0.f);
    float v2 = 0.5f*(x.z + y.z) + (i == j4+2 ? 1.f : 0.f);
    float v3 = 0.5f*(x.w + y.w) + (i == j4+3 ? 1.f : 0.f);
    f16x4 o;
    o[0] = (f16)(di*v0*dj.x); o[1] = (f16)(di*v1*dj.y);
    o[2] = (f16)(di*v2*dj.z); o[3] = (f16)(di*v3*dj.w);
    *(f16x4*)(an + base) = o;
}

// ---------------- NT GEMM, 128x128 tile, 4 waves, mfma 16x16x32_f16, fp32 acc
// BK=64, double-buffered global_load_lds staging (T3-minimum 2-phase):
//   stage(next) issued BEFORE compute(cur); one __syncthreads (vmcnt0+barrier)
//   per K-step drains the prefetch after it overlapped the whole compute phase.
// XOR-swizzled chunks (T2): LDS slot (row,c) holds global chunk c^(row&7);
//   reader uses c=(kk*4+g)^(row&7) -> conflict-free (verified round 4: 0 conflicts).
// A [M][K] row-major f16, Bt [512][K] row-major f16.
// MODE 0: write f16 (T buffer)          grid (128, 4)
// MODE 1: gate epilogue -> Hcat f16     grid (128, 4)
// MODE 2: write f16 transposed -> Yt    grid (128, 4)
// MODE 3: batched adj: +bias, relu ->Hn grid (8, 4, 16)
template<int MODE>
__global__ __launch_bounds__(256) void k_gemm(
    const f16* __restrict__ A, const f16* __restrict__ Bt, int K,
    const f16* __restrict__ Tbuf, const float* __restrict__ entS,
    const float* __restrict__ went, const float* __restrict__ gb,
    const f16* __restrict__ featf, f16* __restrict__ hOut, int hColOff,
    const float* __restrict__ bias)
{
    __shared__ f16 As[2][128*64];   // [buf][row][chunk(8x16B)], 128B row stride
    __shared__ f16 Bs[2][128*64];
    int tid = threadIdx.x;
    int lane = tid & 63, wave = tid >> 6;
    int wr = wave >> 1, wc = wave & 1;
    int m0 = blockIdx.x * 128, n0 = blockIdx.y * 128;
    int z = blockIdx.z;
    if constexpr (MODE == 3) {
        A  += (size_t)z * (1024*1024);
        Bt += (size_t)z * (512*1024);
    }
    // staging source (pre-swizzled): lane covers row m0+wave*32+j*8+(lane>>3),
    // 16B chunk (lane&7)^(lane>>3) of the 128B k-window
    int lrow = lane >> 3;
    int swz  = (lane & 7) ^ lrow;
    const f16* pA = A  + (size_t)(m0 + wave*32 + lrow)*K + swz*8;
    const f16* pB = Bt + (size_t)(n0 + wave*32 + lrow)*K + swz*8;

    f32x4 acc[4][4];
#pragma unroll
    for (int mi = 0; mi < 4; mi++)
#pragma unroll
        for (int ni = 0; ni < 4; ni++) acc[mi][ni] = (f32x4){0.f,0.f,0.f,0.f};
    int g = lane >> 4, r = lane & 15;

    int NT = K >> 6;
    // prologue: stage tile 0 into buf 0
#pragma unroll
    for (int j = 0; j < 4; j++) {
        gl16(&As[0][(wave*4 + j)*512], pA + (size_t)(j*8)*K);
        gl16(&Bs[0][(wave*4 + j)*512], pB + (size_t)(j*8)*K);
    }
    __syncthreads();

    for (int t = 0; t < NT; ++t) {
        int cur = t & 1;
        if (t + 1 < NT) {               // prefetch next tile into other buffer
            int nb = cur ^ 1, kt = (t + 1) << 6;
#pragma unroll
            for (int j = 0; j < 4; j++) {
                gl16(&As[nb][(wave*4 + j)*512], pA + (size_t)(j*8)*K + kt);
                gl16(&Bs[nb][(wave*4 + j)*512], pB + (size_t)(j*8)*K + kt);
            }
        }
#pragma unroll
        for (int kk = 0; kk < 2; kk++) {
            f16x8 af[4], bf[4];
#pragma unroll
            for (int mi = 0; mi < 4; mi++) {
                int row = wr*64 + mi*16 + r;
                int ch = (kk*4 + g) ^ (row & 7);
                af[mi] = *(const f16x8*)&As[cur][row*64 + ch*8];
            }
#pragma unroll
            for (int ni = 0; ni < 4; ni++) {
                int row = wc*64 + ni*16 + r;
                int ch = (kk*4 + g) ^ (row & 7);
                bf[ni] = *(const f16x8*)&Bs[cur][row*64 + ch*8];
            }
#pragma unroll
            for (int mi = 0; mi < 4; mi++)
#pragma unroll
                for (int ni = 0; ni < 4; ni++)
                    acc[mi][ni] = __builtin_amdgcn_mfma_f32_16x16x32_f16(af[mi], bf[ni], acc[mi][ni], 0, 0, 0);
        }
        __syncthreads();                // vmcnt(0)+lgkmcnt(0)+barrier: prefetch
                                        // landed, all waves done reading cur
    }
    // epilogue: C frag mapping col = lane&15, row = (lane>>4)*4 + j   [m89-verified]
#pragma unroll
    for (int mi = 0; mi < 4; mi++) {
        int row0 = m0 + wr*64 + mi*16 + g*4;
#pragma unroll
        for (int ni = 0; ni < 4; ni++) {
            int col = n0 + wc*64 + ni*16 + r;
            f32x4 v = acc[mi][ni];
            if constexpr (MODE == 0) {
#pragma unroll
                for (int j = 0; j < 4; j++)
                    hOut[(size_t)(row0 + j)*512 + col] = (f16)v[j];
            } else if constexpr (MODE == 1) {
                float wcol = went[col], gbc = gb[col];
#pragma unroll
                for (int j = 0; j < 4; j++) {
                    int row = row0 + j;
                    float val = v[j] + (float)Tbuf[(size_t)row*512 + col] + entS[row]*wcol + gbc;
                    float gate = 1.f / (1.f + __expf(-val));
                    float o = gate * (float)featf[(size_t)row*512 + col];
                    hOut[(size_t)row*1536 + hColOff + col] = (f16)o;
                }
            } else if constexpr (MODE == 2) {
                int bb = row0 >> 10, ml = row0 & 1023;
                f16x4 h4;
#pragma unroll
                for (int j = 0; j < 4; j++) h4[j] = (f16)v[j];
                *(f16x4*)(hOut + (((size_t)(bb*512 + col)) << 10) + ml) = h4;
            } else {
                float bcol = bias[col];
#pragma unroll
                for (int j = 0; j < 4; j++) {
                    float o = v[j] + bcol;
                    o = o > 0.f ? o : 0.f;
                    hOut[(size_t)(z*1024 + row0 + j)*512 + col] = (f16)o;
                }
            }
        }
    }
}

// ---------------- classifier: out = h3 @ Wc + bc  (f32 on VALU, tiny)
__global__ __launch_bounds__(256) void k_cls(
    const f16* __restrict__ h, const float* __restrict__ Wc,
    const float* __restrict__ bc, float* __restrict__ out)
{
    int wave = threadIdx.x >> 6, lane = threadIdx.x & 63;
    int row = blockIdx.x * 4 + wave;
    f16x8 hv = *(const f16x8*)(h + (size_t)row*512 + lane*8);
    float acc[7];
#pragma unroll
    for (int c = 0; c < 7; c++) acc[c] = 0.f;
#pragma unroll
    for (int j = 0; j < 8; j++) {
        float x = (float)hv[j];
        const float* wrow = Wc + (size_t)(lane*8 + j)*7;
#pragma unroll
        for (int c = 0; c < 7; c++) acc[c] += x * wrow[c];
    }
#pragma unroll
    for (int off = 32; off; off >>= 1)
#pragma unroll
        for (int c = 0; c < 7; c++) acc[c] += __shfl_xor(acc[c], off);
    if (lane == 0) {
#pragma unroll
        for (int c = 0; c < 7; c++) out[(size_t)row*7 + c] = acc[c] + bc[c];
    }
}

extern "C" void kernel_launch(void* const* d_in, const int* in_sizes, int n_in,
                              void* d_out, int out_size, void* d_ws, size_t ws_size,
                              hipStream_t stream) {
    (void)in_sizes; (void)n_in; (void)out_size; (void)ws_size;
    const float* text   = (const float*)d_in[0];
    const float* audio  = (const float*)d_in[1];
    const float* visual = (const float*)d_in[2];
    const float* spg    = (const float*)d_in[3];
    const float* tmg    = (const float*)d_in[4];
    const float* gW     = (const float*)d_in[6];
    const float* gb     = (const float*)d_in[7];
    const float* W0     = (const float*)d_in[8];
    const float* b0     = (const float*)d_in[9];
    const float* W1     = (const float*)d_in[10];
    const float* b1     = (const float*)d_in[11];
    const float* W2     = (const float*)d_in[12];
    const float* b2     = (const float*)d_in[13];
    const float* Wc     = (const float*)d_in[14];
    const float* bc     = (const float*)d_in[15];

    char* ws = (char*)d_ws;
    f16*   Wg1t = (f16*)(ws + OFF_WG1T);
    f16*   Wg2t = (f16*)(ws + OFF_WG2T);
    f16*   W0t  = (f16*)(ws + OFF_W0T);
    f16*   W1t  = (f16*)(ws + OFF_W1T);
    f16*   W2t  = (f16*)(ws + OFF_W2T);
    float* went = (float*)(ws + OFF_WENT);
    float* ents = (float*)(ws + OFF_ENTS);
    float* dsi  = (float*)(ws + OFF_DSI);
    f16*   xf   = (f16*)(ws + OFF_XF16);
    f16*   an   = (f16*)(ws + OFF_ANORM);
    f16*   hn   = (f16*)(ws + OFF_HN);
    f16*   Tbuf = (f16*)(ws + OFF_T);
    f16*   yt   = (f16*)(ws + OFF_YT);
    f16*   hcat = (f16*)(ws + OFF_HCAT);
    float* outp = (float*)d_out;

    dim3 blk(256);
    // prep + elementwise
    k_prep<<<3072, blk, 0, stream>>>(gW, W0, W1, W2, Wg1t, Wg2t, W0t, W1t, W2t, went);
    k_ent<<<4096, blk, 0, stream>>>(text, audio, visual, xf, ents);
    k_dsi<<<4096, blk, 0, stream>>>(spg, tmg, dsi);

    // T = Fsum @ Wg2 -> f16 Tbuf
    k_gemm<0><<<dim3(128,4), blk, 0, stream>>>(xf + 3*PLANE, Wg2t, 512,
        nullptr, nullptr, nullptr, nullptr, nullptr, Tbuf, 0, nullptr);
    // gates -> Hcat (f16 feat multiplicand from xf planes)
    k_gemm<1><<<dim3(128,4), blk, 0, stream>>>(xf + 0*PLANE, Wg1t, 512,
        Tbuf, ents + 0*MQ, went, gb, xf + 0*PLANE, hcat, 0,    nullptr);
    k_gemm<1><<<dim3(128,4), blk, 0, stream>>>(xf + 1*PLANE, Wg1t, 512,
        Tbuf, ents + 1*MQ, went, gb, xf + 1*PLANE, hcat, 512,  nullptr);
    k_gemm<1><<<dim3(128,4), blk, 0, stream>>>(xf + 2*PLANE, Wg1t, 512,
        Tbuf, ents + 2*MQ, went, gb, xf + 2*PLANE, hcat, 1024, nullptr);

    // norm_adj (aliases XF16 planes 0-1 — safe now that gates are done)
    k_anorm<<<16384, blk, 0, stream>>>(spg, tmg, dsi, an);

    // layer 0
    k_gemm<2><<<dim3(128,4), blk, 0, stream>>>(hcat, W0t, 1536,
        nullptr, nullptr, nullptr, nullptr, nullptr, yt, 0, nullptr);
    k_gemm<3><<<dim3(8,4,16), blk, 0, stream>>>(an, yt, 1024,
        nullptr, nullptr, nullptr, nullptr, nullptr, hn, 0, b0);
    // layer 1
    k_gemm<2><<<dim3(128,4), blk, 0, stream>>>(hn, W1t, 512,
        nullptr, nullptr, nullptr, nullptr, nullptr, yt, 0, nullptr);
    k_gemm<3><<<dim3(8,4,16), blk, 0, stream>>>(an, yt, 1024,
        nullptr, nullptr, nullptr, nullptr, nullptr, hn, 0, b1);
    // layer 2
    k_gemm<2><<<dim3(128,4), blk, 0, stream>>>(hn, W2t, 512,
        nullptr, nullptr, nullptr, nullptr, nullptr, yt, 0, nullptr);
    k_gemm<3><<<dim3(8,4,16), blk, 0, stream>>>(an, yt, 1024,
        nullptr, nullptr, nullptr, nullptr, nullptr, hn, 0, b2);

    // classifier
    k_cls<<<4096, blk, 0, stream>>>(hn, Wc, bc, outp);
}

// Round 7
// 533.136 us; speedup vs baseline: 1.0362x; 1.0362x over previous
//
#include <hip/hip_runtime.h>
#include <hip/hip_bf16.h>
#include <hip/hip_fp16.h>

typedef _Float16 f16;
typedef __attribute__((ext_vector_type(8))) _Float16 f16x8;
typedef __attribute__((ext_vector_type(4))) _Float16 f16x4;
typedef __attribute__((ext_vector_type(4))) float f32x4;
typedef __attribute__((address_space(1))) const unsigned int gu32;
typedef __attribute__((address_space(3))) unsigned int lu32;

#define BQ 16
#define SQ 1024
#define HQ 512
#define MQ (BQ*SQ)          // 16384 rows total
#define PLANE ((size_t)MQ*512)

// ---- workspace layout (bytes). Aliasing:
//   ANORM aliases XF16 planes 0-1 (dead after gate GEMMs)
//   HN    aliases XF16 plane 2 (first written by MODE3-L0, after gates)
//   YT    aliases T    (T dead after gate GEMMs)
#define OFF_WG1T 0ul
#define OFF_WG2T 524288ul
#define OFF_W0T  1048576ul
#define OFF_W1T  2621440ul
#define OFF_W2T  3145728ul
#define OFF_WENT 3670016ul
#define OFF_ENTS 3672064ul
#define OFF_DSI  3868672ul
#define OFF_XF16 3934208ul
#define OFF_ANORM OFF_XF16
#define OFF_HN   (OFF_XF16 + 33554432ul)
#define OFF_T    71043072ul
#define OFF_YT   OFF_T
#define OFF_HCAT 104597504ul
// total = 104597504 + 50331648 = 154929152 bytes (~148 MB)

// async global->LDS, 16B per lane; LDS dest is wave-uniform base + lane*16
__device__ __forceinline__ void gl16(f16* lds, const f16* g) {
    __builtin_amdgcn_global_load_lds(
        (gu32*)(const __attribute__((address_space(1))) f16*)g,
        (lu32*)(__attribute__((address_space(3))) f16*)lds, 16, 0, 0);
}

// ---------------- mega prep kernel: [ent 4096 | dsi 4096 | prep 3072] blocks
__global__ __launch_bounds__(256) void k_pre(
    const float* __restrict__ t, const float* __restrict__ a, const float* __restrict__ v,
    const float* __restrict__ sp, const float* __restrict__ tg,
    const float* __restrict__ gW, const float* __restrict__ W0,
    const float* __restrict__ W1, const float* __restrict__ W2,
    f16* __restrict__ xf, float* __restrict__ ents, float* __restrict__ dsi,
    f16* __restrict__ Wg1t, f16* __restrict__ Wg2t, f16* __restrict__ W0t,
    f16* __restrict__ W1t, f16* __restrict__ W2t, float* __restrict__ went)
{
    int bid = blockIdx.x;
    int wave = threadIdx.x >> 6, lane = threadIdx.x & 63;
    if (bid < 4096) {
        // ---- entropy + f16 casts + sum plane (single-pass identity)
        int row = bid * 4 + wave;
        const float* ptrs[3] = {t, a, v};
        float4 x[3][2];
#pragma unroll
        for (int m = 0; m < 3; m++) {
            const float4* p = (const float4*)(ptrs[m] + (size_t)row*512);
            x[m][0] = p[lane*2];
            x[m][1] = p[lane*2 + 1];
        }
        float s[3], tt[3];
#pragma unroll
        for (int m = 0; m < 3; m++) {
            float xs[8] = {x[m][0].x,x[m][0].y,x[m][0].z,x[m][0].w,
                           x[m][1].x,x[m][1].y,x[m][1].z,x[m][1].w};
            s[m] = 0.f; tt[m] = 0.f;
#pragma unroll
            for (int j = 0; j < 8; j++) {
                float ab = fabsf(xs[j]);
                s[m]  += ab;
                tt[m] += ab * __logf(ab + 1e-12f);
            }
        }
#pragma unroll
        for (int off = 32; off; off >>= 1) {
#pragma unroll
            for (int m = 0; m < 3; m++) {
                s[m]  += __shfl_xor(s[m],  off);
                tt[m] += __shfl_xor(tt[m], off);
            }
        }
        if (lane == 0) {
#pragma unroll
            for (int m = 0; m < 3; m++) {
                float spp = s[m] + 1e-10f;
                ents[m*MQ + row] = __logf(spp) * (s[m]/spp) - tt[m]/spp;
            }
        }
        float sum8[8];
#pragma unroll
        for (int j = 0; j < 8; j++) sum8[j] = 0.f;
#pragma unroll
        for (int m = 0; m < 3; m++) {
            float xs[8] = {x[m][0].x,x[m][0].y,x[m][0].z,x[m][0].w,
                           x[m][1].x,x[m][1].y,x[m][1].z,x[m][1].w};
            f16x8 o;
#pragma unroll
            for (int j = 0; j < 8; j++) { o[j] = (f16)xs[j]; sum8[j] += xs[j]; }
            *(f16x8*)(xf + ((size_t)m*MQ + row)*512 + lane*8) = o;
        }
        f16x8 o;
#pragma unroll
        for (int j = 0; j < 8; j++) o[j] = (f16)sum8[j];
        *(f16x8*)(xf + ((size_t)3*MQ + row)*512 + lane*8) = o;
    } else if (bid < 8192) {
        // ---- dsi = (rowsum(0.5*(sp+tg)) + 1 + eps)^-1/2
        int row = (bid - 4096) * 4 + wave;
        const float4* p1 = (const float4*)(sp + (size_t)row*1024);
        const float4* p2 = (const float4*)(tg + (size_t)row*1024);
        float s = 0.f;
#pragma unroll
        for (int c = 0; c < 4; c++) {
            float4 x = p1[c*64 + lane], y = p2[c*64 + lane];
            s += x.x + x.y + x.z + x.w + y.x + y.y + y.z + y.w;
        }
#pragma unroll
        for (int off = 32; off; off >>= 1) s += __shfl_xor(s, off);
        if (lane == 0) dsi[row] = 1.f / sqrtf(0.5f*s + 1.f + 1e-10f);
    } else {
        // ---- weight prep: fold gate algebra, transpose to [N][K], cast f16
        int i = (bid - 8192) * 256 + threadIdx.x;   // covers 1536*512
        {
            int n = i & 511, k = i >> 9;            // k < 1536
            W0t[(size_t)n*1536 + k] = (f16)W0[(size_t)k*512 + n];
        }
        if (i < 512*512) {
            int n = i >> 9, k = i & 511;
            float wa = gW[(size_t)k*512 + n];
            float wb = gW[(size_t)(512 + k)*512 + n];
            float wr = gW[(size_t)(1024 + k)*512 + n];
            Wg1t[(size_t)n*512 + k] = (f16)(wa + wb - 0.5f*wr);
            Wg2t[(size_t)n*512 + k] = (f16)(0.5f*wr);
            W1t[(size_t)n*512 + k]  = (f16)W1[(size_t)k*512 + n];
            W2t[(size_t)n*512 + k]  = (f16)W2[(size_t)k*512 + n];
        }
        if (i < 512) went[i] = gW[(size_t)1536*512 + i];
    }
}

// ---------------- norm_adj build (f16)
__global__ __launch_bounds__(256) void k_anorm(
    const float* __restrict__ sp, const float* __restrict__ tg,
    const float* __restrict__ dsi, f16* __restrict__ an)
{
    size_t t = (size_t)blockIdx.x*256 + threadIdx.x;   // 4 elems per thread
    int j4 = (int)(t & 255) * 4;
    int i  = (int)(t >> 8) & 1023;
    int b  = (int)(t >> 18);
    size_t base = ((size_t)b << 20) + (size_t)i*1024 + j4;
    float4 x = *(const float4*)(sp + base);
    float4 y = *(const float4*)(tg + base);
    float4 dj = *(const float4*)(dsi + b*1024 + j4);
    float di = dsi[b*1024 + i];
    float v0 = 0.5f*(x.x + y.x) + (i == j4+0 ? 1.f : 0.f);
    float v1 = 0.5f*(x.y + y.y) + (i == j4+1 ? 1.f : 0.f);
    float v2 = 0.5f*(x.z + y.z) + (i == j4+2 ? 1.f : 0.f);
    float v3 = 0.5f*(x.w + y.w) + (i == j4+3 ? 1.f : 0.f);
    f16x4 o;
    o[0] = (f16)(di*v0*dj.x); o[1] = (f16)(di*v1*dj.y);
    o[2] = (f16)(di*v2*dj.z); o[3] = (f16)(di*v3*dj.w);
    *(f16x4*)(an + base) = o;
}

// ---------------- NT GEMM, 128x128 tile, 4 waves, mfma 16x16x32_f16, fp32 acc
// BK=32, TRIPLE-buffered global_load_lds staging, counted vmcnt (T4):
//   steady state keeps 8 loads (2 tiles) in flight; vmcnt(4) at iter top waits
//   only the current tile. lgkmcnt(0)+sched_barrier before raw s_barrier
//   (rule #18); stage(t+2) goes into buf[(t+2)%3] = tile t-1's buffer, whose
//   readers all finished before this iteration's barrier.
// Swizzle (64B rows, 4 chunks): slot = g ^ ((r>>1)&3) -> every bank-quad hit
//   exactly 2x per quarter-wave = free [m136]. Stage source pre-swizzled:
//   chunk (l&3)^((l>>3)&3).
// A [M][K] row-major f16, Bt [512][K] row-major f16.
// MODE 0: write f16 (T buffer)          grid (128, 4)
// MODE 1: gate epilogue -> Hcat f16     grid (128, 4, 3)  z = modality
// MODE 2: write f16 transposed -> Yt    grid (128, 4)
// MODE 3: batched adj: +bias, relu ->Hn grid (8, 4, 16)   z = batch
template<int MODE>
__global__ __launch_bounds__(256) void k_gemm(
    const f16* __restrict__ A, const f16* __restrict__ Bt, int K,
    const f16* __restrict__ Tbuf, const float* __restrict__ entS,
    const float* __restrict__ went, const float* __restrict__ gb,
    const f16* __restrict__ featf, f16* __restrict__ hOut, int hColOff,
    const float* __restrict__ bias)
{
    __shared__ f16 S[3*8192];      // 3 bufs x (A 4096 | B 4096) f16 = 48 KB
    int tid = threadIdx.x;
    int lane = tid & 63, wave = tid >> 6;
    int wr = wave >> 1, wc = wave & 1;
    int m0 = blockIdx.x * 128, n0 = blockIdx.y * 128;
    int z = blockIdx.z;
    if constexpr (MODE == 1) {
        A     += (size_t)z * PLANE;
        entS  += (size_t)z * MQ;
        featf += (size_t)z * PLANE;
        hColOff = z * 512;
    }
    if constexpr (MODE == 3) {
        A  += (size_t)z * (1024*1024);
        Bt += (size_t)z * (512*1024);
    }
    // staging source (pre-swizzled): lane l covers row base+(l>>2),
    // 16B chunk (l&3)^((l>>3)&3) of the 64B k-window; phase j adds 16 rows.
    int swz = (lane & 3) ^ ((lane >> 3) & 3);
    const f16* pA = A  + (size_t)(m0 + wave*32 + (lane >> 2))*K + swz*8;
    const f16* pB = Bt + (size_t)(n0 + wave*32 + (lane >> 2))*K + swz*8;
    f16* ldsA = S + (size_t)(wave*2)*512;        // + buf*8192; phase j adds 512
    f16* ldsB = ldsA + 4096;

    f32x4 acc[4][4];
#pragma unroll
    for (int mi = 0; mi < 4; mi++)
#pragma unroll
        for (int ni = 0; ni < 4; ni++) acc[mi][ni] = (f32x4){0.f,0.f,0.f,0.f};
    int g = lane >> 4, r = lane & 15;
    int sl = (g ^ ((r >> 1) & 3)) * 8;           // swizzled chunk slot (f16 units)

    int NT = K >> 5;                             // BK=32 tiles
#define STAGE(sb, tt) {                                        \
        int kt_ = (tt) << 5;                                   \
        f16* la_ = ldsA + (sb)*8192;                           \
        f16* lb_ = ldsB + (sb)*8192;                           \
        gl16(la_,        pA + kt_);                            \
        gl16(la_ + 512,  pA + (size_t)16*K + kt_);             \
        gl16(lb_,        pB + kt_);                            \
        gl16(lb_ + 512,  pB + (size_t)16*K + kt_);             \
    }
    // prologue: 2 tiles in flight
    STAGE(0, 0);
    STAGE(1, 1);
    int cur = 0, sb = 2;
    for (int t = 0; t < NT; ++t) {
        asm volatile("s_waitcnt lgkmcnt(0)" ::: "memory");   // prior ds_reads done
        if (t + 1 < NT) asm volatile("s_waitcnt vmcnt(4)" ::: "memory");
        else            asm volatile("s_waitcnt vmcnt(0)" ::: "memory");
        __builtin_amdgcn_sched_barrier(0);
        __builtin_amdgcn_s_barrier();
        __builtin_amdgcn_sched_barrier(0);
        if (t + 2 < NT) STAGE(sb, t + 2);
        const f16* As_ = S + cur*8192;
        const f16* Bs_ = As_ + 4096;
        f16x8 af[4], bf[4];
#pragma unroll
        for (int mi = 0; mi < 4; mi++)
            af[mi] = *(const f16x8*)&As_[(wr*64 + mi*16 + r)*32 + sl];
#pragma unroll
        for (int ni = 0; ni < 4; ni++)
            bf[ni] = *(const f16x8*)&Bs_[(wc*64 + ni*16 + r)*32 + sl];
#pragma unroll
        for (int mi = 0; mi < 4; mi++)
#pragma unroll
            for (int ni = 0; ni < 4; ni++)
                acc[mi][ni] = __builtin_amdgcn_mfma_f32_16x16x32_f16(af[mi], bf[ni], acc[mi][ni], 0, 0, 0);
        cur = cur == 2 ? 0 : cur + 1;
        sb  = sb  == 2 ? 0 : sb  + 1;
    }
#undef STAGE
    // epilogue: C frag mapping col = lane&15, row = (lane>>4)*4 + j   [m89-verified]
#pragma unroll
    for (int mi = 0; mi < 4; mi++) {
        int row0 = m0 + wr*64 + mi*16 + g*4;
#pragma unroll
        for (int ni = 0; ni < 4; ni++) {
            int col = n0 + wc*64 + ni*16 + r;
            f32x4 v = acc[mi][ni];
            if constexpr (MODE == 0) {
#pragma unroll
                for (int j = 0; j < 4; j++)
                    hOut[(size_t)(row0 + j)*512 + col] = (f16)v[j];
            } else if constexpr (MODE == 1) {
                float wcol = went[col], gbc = gb[col];
#pragma unroll
                for (int j = 0; j < 4; j++) {
                    int row = row0 + j;
                    float val = v[j] + (float)Tbuf[(size_t)row*512 + col] + entS[row]*wcol + gbc;
                    float gate = 1.f / (1.f + __expf(-val));
                    float o = gate * (float)featf[(size_t)row*512 + col];
                    hOut[(size_t)row*1536 + hColOff + col] = (f16)o;
                }
            } else if constexpr (MODE == 2) {
                int bb = row0 >> 10, ml = row0 & 1023;
                f16x4 h4;
#pragma unroll
                for (int j = 0; j < 4; j++) h4[j] = (f16)v[j];
                *(f16x4*)(hOut + (((size_t)(bb*512 + col)) << 10) + ml) = h4;
            } else {
                float bcol = bias[col];
#pragma unroll
                for (int j = 0; j < 4; j++) {
                    float o = v[j] + bcol;
                    o = o > 0.f ? o : 0.f;
                    hOut[(size_t)(z*1024 + row0 + j)*512 + col] = (f16)o;
                }
            }
        }
    }
}

// ---------------- classifier: out = h3 @ Wc + bc  (f32 on VALU, tiny)
__global__ __launch_bounds__(256) void k_cls(
    const f16* __restrict__ h, const float* __restrict__ Wc,
    const float* __restrict__ bc, float* __restrict__ out)
{
    int wave = threadIdx.x >> 6, lane = threadIdx.x & 63;
    int row = blockIdx.x * 4 + wave;
    f16x8 hv = *(const f16x8*)(h + (size_t)row*512 + lane*8);
    float acc[7];
#pragma unroll
    for (int c = 0; c < 7; c++) acc[c] = 0.f;
#pragma unroll
    for (int j = 0; j < 8; j++) {
        float x = (float)hv[j];
        const float* wrow = Wc + (size_t)(lane*8 + j)*7;
#pragma unroll
        for (int c = 0; c < 7; c++) acc[c] += x * wrow[c];
    }
#pragma unroll
    for (int off = 32; off; off >>= 1)
#pragma unroll
        for (int c = 0; c < 7; c++) acc[c] += __shfl_xor(acc[c], off);
    if (lane == 0) {
#pragma unroll
        for (int c = 0; c < 7; c++) out[(size_t)row*7 + c] = acc[c] + bc[c];
    }
}

extern "C" void kernel_launch(void* const* d_in, const int* in_sizes, int n_in,
                              void* d_out, int out_size, void* d_ws, size_t ws_size,
                              hipStream_t stream) {
    (void)in_sizes; (void)n_in; (void)out_size; (void)ws_size;
    const float* text   = (const float*)d_in[0];
    const float* audio  = (const float*)d_in[1];
    const float* visual = (const float*)d_in[2];
    const float* spg    = (const float*)d_in[3];
    const float* tmg    = (const float*)d_in[4];
    const float* gW     = (const float*)d_in[6];
    const float* gb     = (const float*)d_in[7];
    const float* W0     = (const float*)d_in[8];
    const float* b0     = (const float*)d_in[9];
    const float* W1     = (const float*)d_in[10];
    const float* b1     = (const float*)d_in[11];
    const float* W2     = (const float*)d_in[12];
    const float* b2     = (const float*)d_in[13];
    const float* Wc     = (const float*)d_in[14];
    const float* bc     = (const float*)d_in[15];

    char* ws = (char*)d_ws;
    f16*   Wg1t = (f16*)(ws + OFF_WG1T);
    f16*   Wg2t = (f16*)(ws + OFF_WG2T);
    f16*   W0t  = (f16*)(ws + OFF_W0T);
    f16*   W1t  = (f16*)(ws + OFF_W1T);
    f16*   W2t  = (f16*)(ws + OFF_W2T);
    float* went = (float*)(ws + OFF_WENT);
    float* ents = (float*)(ws + OFF_ENTS);
    float* dsi  = (float*)(ws + OFF_DSI);
    f16*   xf   = (f16*)(ws + OFF_XF16);
    f16*   an   = (f16*)(ws + OFF_ANORM);
    f16*   hn   = (f16*)(ws + OFF_HN);
    f16*   Tbuf = (f16*)(ws + OFF_T);
    f16*   yt   = (f16*)(ws + OFF_YT);
    f16*   hcat = (f16*)(ws + OFF_HCAT);
    float* outp = (float*)d_out;

    dim3 blk(256);
    // mega prep: ent (4096) | dsi (4096) | weight-prep (3072)
    k_pre<<<11264, blk, 0, stream>>>(text, audio, visual, spg, tmg, gW, W0, W1, W2,
        xf, ents, dsi, Wg1t, Wg2t, W0t, W1t, W2t, went);

    // T = Fsum @ Wg2 -> f16 Tbuf
    k_gemm<0><<<dim3(128,4), blk, 0, stream>>>(xf + 3*PLANE, Wg2t, 512,
        nullptr, nullptr, nullptr, nullptr, nullptr, Tbuf, 0, nullptr);
    // gates -> Hcat, all 3 modalities in one dispatch (z)
    k_gemm<1><<<dim3(128,4,3), blk, 0, stream>>>(xf, Wg1t, 512,
        Tbuf, ents, went, gb, xf, hcat, 0, nullptr);

    // norm_adj (aliases XF16 planes 0-1 — safe now that gates are done)
    k_anorm<<<16384, blk, 0, stream>>>(spg, tmg, dsi, an);

    // layer 0
    k_gemm<2><<<dim3(128,4), blk, 0, stream>>>(hcat, W0t, 1536,
        nullptr, nullptr, nullptr, nullptr, nullptr, yt, 0, nullptr);
    k_gemm<3><<<dim3(8,4,16), blk, 0, stream>>>(an, yt, 1024,
        nullptr, nullptr, nullptr, nullptr, nullptr, hn, 0, b0);
    // layer 1
    k_gemm<2><<<dim3(128,4), blk, 0, stream>>>(hn, W1t, 512,
        nullptr, nullptr, nullptr, nullptr, nullptr, yt, 0, nullptr);
    k_gemm<3><<<dim3(8,4,16), blk, 0, stream>>>(an, yt, 1024,
        nullptr, nullptr, nullptr, nullptr, nullptr, hn, 0, b1);
    // layer 2
    k_gemm<2><<<dim3(128,4), blk, 0, stream>>>(hn, W2t, 512,
        nullptr, nullptr, nullptr, nullptr, nullptr, yt, 0, nullptr);
    k_gemm<3><<<dim3(8,4,16), blk, 0, stream>>>(an, yt, 1024,
        nullptr, nullptr, nullptr, nullptr, nullptr, hn, 0, b2);

    // classifier
    k_cls<<<4096, blk, 0, stream>>>(hn, Wc, bc, outp);
}